// Round 7
// baseline (753.111 us; speedup 1.0000x reference)
//
#include <hip/hip_runtime.h>

#define T2 128
#define NB 16
#define LOG2E 1.44269504088896340736f
#define LN2   0.69314718055994530942f

typedef _Float16 f16;
typedef __attribute__((ext_vector_type(2))) _Float16 f16x2;
typedef __attribute__((ext_vector_type(8))) _Float16 f16x8;
typedef __attribute__((ext_vector_type(4))) float f32x4;

__device__ __forceinline__ unsigned pkrtz(float a, float b) {
  return __builtin_bit_cast(unsigned, __builtin_amdgcn_cvt_pkrtz(a, b));
}
__device__ __forceinline__ unsigned pkmul(unsigned a, unsigned b) {
  return __builtin_bit_cast(unsigned,
      (f16x2)(__builtin_bit_cast(f16x2, a) * __builtin_bit_cast(f16x2, b)));
}
__device__ __forceinline__ float ex2(float x) { return __builtin_amdgcn_exp2f(x); }

// ONE WAVE per 16 chains: 16 blocks x 64 threads, ZERO barriers.
// Per step: 32 MFMA 16x16x32 f16 (M=128 to, N=16 chains, K=128 from),
// q' = C * ef packed f16, LDS roundtrip within the wave (in-order pipe).
// A = exp2(trans*log2e - 8) in regs (2^-8/step damping lives in A).
// feats prefetched 2 steps ahead; exp'd late; l1-rescale every 8 steps
// folded into next step's ef regs. Interleaved write/read: B'[kk] read
// right after m-tiles 2kk,2kk+1 written.
__global__ __launch_bounds__(64, 1)
void crf_fwd(const float* __restrict__ feats,
             const float* __restrict__ trans,
             float* __restrict__ out, int S) {
  const int l  = threadIdx.x;
  const int c  = l & 15;   // chain (N), also A/B row/col within 16
  const int g  = l >> 4;   // k-group / C-row-group
  const int b0 = blockIdx.x * NB;

  __shared__ __align__(16) unsigned char bufA[4096];
  __shared__ __align__(16) unsigned char bufB[4096];

  // LDS byte offsets, XOR-swizzled (<=2-way bank aliasing = free)
  int wroff[8], rdoff[4];
#pragma unroll
  for (int mt = 0; mt < 8; ++mt)
    wroff[mt] = ((c << 8) + ((16 * mt + 4 * g) << 1)) ^ ((c & 7) << 4);
#pragma unroll
  for (int kk = 0; kk < 4; ++kk)
    rdoff[kk] = ((c << 8) + ((32 * kk + 8 * g) << 1)) ^ ((c & 7) << 4);

  // ---- A frags: A[mt][kk] slot j = exp2(trans[16mt+c][32kk+8g+j]*L2E - 8)
  f16x8 A[8][4];
#pragma unroll
  for (int mt = 0; mt < 8; ++mt) {
#pragma unroll
    for (int kk = 0; kk < 4; ++kk) {
      const float* r = trans + (size_t)(16 * mt + c) * T2 + 32 * kk + 8 * g;
      float4 u0 = *(const float4*)r;
      float4 u1 = *(const float4*)(r + 4);
      f16x8 a;
      a[0] = (f16)ex2(fmaf(u0.x, LOG2E, -8.f));
      a[1] = (f16)ex2(fmaf(u0.y, LOG2E, -8.f));
      a[2] = (f16)ex2(fmaf(u0.z, LOG2E, -8.f));
      a[3] = (f16)ex2(fmaf(u0.w, LOG2E, -8.f));
      a[4] = (f16)ex2(fmaf(u1.x, LOG2E, -8.f));
      a[5] = (f16)ex2(fmaf(u1.y, LOG2E, -8.f));
      a[6] = (f16)ex2(fmaf(u1.z, LOG2E, -8.f));
      a[7] = (f16)ex2(fmaf(u1.w, LOG2E, -8.f));
      A[mt][kk] = a;
    }
  }

  // ---- q0: zero bufA, one-hot f16 1.0 at [c][k=127] (single wave: in-order)
#pragma unroll
  for (int i = 0; i < 4; ++i)
    *(uint4*)(bufA + l * 16 + i * 1024) = make_uint4(0, 0, 0, 0);
  if (l < 16)
    *(unsigned short*)(bufA + ((((l << 8) + 254)) ^ ((l & 7) << 4))) = 0x3C00;

  unsigned BX[16], BY[16];
#pragma unroll
  for (int kk = 0; kk < 4; ++kk) {
    uint4 u = *(const uint4*)(bufA + rdoff[kk]);
    BX[kk * 4 + 0] = u.x; BX[kk * 4 + 1] = u.y;
    BX[kk * 4 + 2] = u.z; BX[kk * 4 + 3] = u.w;
  }

  const float* fb = feats + ((size_t)(b0 + c) * S) * T2 + 4 * g;
  float4 PA[8], PB[8];
#pragma unroll
  for (int mt = 0; mt < 8; ++mt) PA[mt] = *(const float4*)(fb + 16 * mt);
#pragma unroll
  for (int mt = 0; mt < 8; ++mt) PB[mt] = *(const float4*)(fb + T2 + 16 * mt);
  unsigned EA[16], EB[16];
#pragma unroll
  for (int mt = 0; mt < 8; ++mt) {
    EA[2 * mt]     = pkrtz(ex2(PA[mt].x * LOG2E), ex2(PA[mt].y * LOG2E));
    EA[2 * mt + 1] = pkrtz(ex2(PA[mt].z * LOG2E), ex2(PA[mt].w * LOG2E));
  }

  float log2acc = 0.f;

#define BODY(T, BUFW, BIN, BOUT, PC, PN, EC, EN)                               \
  {                                                                            \
    const int t_ = (T);                                                        \
    /* prefetch feats(t+2) */                                                  \
    {                                                                          \
      int tl = t_ + 2; if (tl > S - 1) tl = S - 1;                             \
      const float* fp_ = fb + (size_t)tl * T2;                                 \
      _Pragma("unroll")                                                        \
      for (int mt = 0; mt < 8; ++mt) PC[mt] = *(const float4*)(fp_ + 16 * mt); \
    }                                                                          \
    unsigned qd[16];                                                           \
    _Pragma("unroll")                                                          \
    for (int mt = 0; mt < 8; ++mt) {                                           \
      f32x4 acc = {0.f, 0.f, 0.f, 0.f};                                        \
      _Pragma("unroll")                                                        \
      for (int kk = 0; kk < 4; ++kk) {                                         \
        uint4 bu = make_uint4(BIN[kk * 4 + 0], BIN[kk * 4 + 1],                \
                              BIN[kk * 4 + 2], BIN[kk * 4 + 3]);               \
        acc = __builtin_amdgcn_mfma_f32_16x16x32_f16(                          \
            A[mt][kk], __builtin_bit_cast(f16x8, bu), acc, 0, 0, 0);           \
      }                                                                        \
      qd[2 * mt]     = pkmul(pkrtz(acc[0], acc[1]), EC[2 * mt]);               \
      qd[2 * mt + 1] = pkmul(pkrtz(acc[2], acc[3]), EC[2 * mt + 1]);           \
      *(uint2*)(BUFW + wroff[mt]) = make_uint2(qd[2 * mt], qd[2 * mt + 1]);    \
      if (mt & 1) { /* B'[kk=mt>>1] ready: m-tiles 2kk,2kk+1 written */        \
        uint4 u = *(const uint4*)(BUFW + rdoff[mt >> 1]);                      \
        BOUT[(mt >> 1) * 4 + 0] = u.x; BOUT[(mt >> 1) * 4 + 1] = u.y;          \
        BOUT[(mt >> 1) * 4 + 2] = u.z; BOUT[(mt >> 1) * 4 + 3] = u.w;          \
      }                                                                        \
    }                                                                          \
    /* exp feats(t+1) -> EN (late: max global-load window) */                  \
    _Pragma("unroll")                                                          \
    for (int mt = 0; mt < 8; ++mt) {                                           \
      EN[2 * mt]     = pkrtz(ex2(PN[mt].x * LOG2E), ex2(PN[mt].y * LOG2E));    \
      EN[2 * mt + 1] = pkrtz(ex2(PN[mt].z * LOG2E), ex2(PN[mt].w * LOG2E));    \
    }                                                                          \
    /* l1 rescale every 8 steps, folded into EN (applied at t+1) */            \
    if (((t_ & 7) == 7) && (t_ != S - 1)) {                                    \
      f16x2 sv = __builtin_bit_cast(f16x2, qd[0]);                             \
      _Pragma("unroll")                                                        \
      for (int i = 1; i < 16; ++i) sv = sv + __builtin_bit_cast(f16x2, qd[i]); \
      float s_ = (float)sv.x + (float)sv.y;                                    \
      s_ += __shfl_xor(s_, 16);                                                \
      s_ += __shfl_xor(s_, 32);                                                \
      s_ = fmaxf(s_, 1e-4f); /* log the SAME clamped s we apply */             \
      float inv_ = 1.0f / s_;                                                  \
      unsigned ip_ = pkrtz(inv_, inv_);                                        \
      _Pragma("unroll")                                                        \
      for (int i = 0; i < 16; ++i) EN[i] = pkmul(EN[i], ip_);                  \
      log2acc += __builtin_amdgcn_logf(s_);                                    \
    }                                                                          \
  }

  for (int t = 0; t < S; t += 2) {
    BODY(t,     bufB, BX, BY, PA, PB, EA, EB)
    BODY(t + 1, bufA, BY, BX, PB, PA, EB, EA)
  }
#undef BODY

  // ---- epilogue: BX holds q_S frags; dot with eend = exp2(trans[END][k]*L2E)
  float p = 0.f;
#pragma unroll
  for (int kk = 0; kk < 4; ++kk) {
    const float* r = trans + (size_t)(T2 - 2) * T2 + 32 * kk + 8 * g;
    float4 u0 = *(const float4*)r;
    float4 u1 = *(const float4*)(r + 4);
    f16x2 h0 = __builtin_bit_cast(f16x2, BX[kk * 4 + 0]);
    f16x2 h1 = __builtin_bit_cast(f16x2, BX[kk * 4 + 1]);
    f16x2 h2 = __builtin_bit_cast(f16x2, BX[kk * 4 + 2]);
    f16x2 h3 = __builtin_bit_cast(f16x2, BX[kk * 4 + 3]);
    p += (float)h0.x * ex2(u0.x * LOG2E) + (float)h0.y * ex2(u0.y * LOG2E);
    p += (float)h1.x * ex2(u0.z * LOG2E) + (float)h1.y * ex2(u0.w * LOG2E);
    p += (float)h2.x * ex2(u1.x * LOG2E) + (float)h2.y * ex2(u1.y * LOG2E);
    p += (float)h3.x * ex2(u1.z * LOG2E) + (float)h3.y * ex2(u1.w * LOG2E);
  }
  p += __shfl_xor(p, 16);
  p += __shfl_xor(p, 32);
  if (l < 16)
    out[b0 + l] =
        (__builtin_amdgcn_logf(fmaxf(p, 1e-30f)) + log2acc + 8.0f * (float)S) * LN2;
}

extern "C" void kernel_launch(void* const* d_in, const int* in_sizes, int n_in,
                              void* d_out, int out_size, void* d_ws, size_t ws_size,
                              hipStream_t stream) {
  const float* feats = (const float*)d_in[0];
  const float* trans = (const float*)d_in[1];
  float* out = (float*)d_out;
  const int B = out_size;                // 256
  const int S = in_sizes[0] / (B * T2);  // 1024
  crf_fwd<<<dim3(B / NB), dim3(64), 0, stream>>>(feats, trans, out, S);
}

// Round 9
// 555.910 us; speedup vs baseline: 1.3547x; 1.3547x over previous
//
#include <hip/hip_runtime.h>

#define T2 128
#define NB 16
#define LOG2E 1.44269504088896340736f
#define LN2   0.69314718055994530942f

typedef _Float16 f16;
typedef __attribute__((ext_vector_type(2))) _Float16 f16x2;
typedef __attribute__((ext_vector_type(8))) _Float16 f16x8;
typedef __attribute__((ext_vector_type(4))) float f32x4;

__device__ __forceinline__ unsigned pkrtz(float a, float b) {
  return __builtin_bit_cast(unsigned, __builtin_amdgcn_cvt_pkrtz(a, b));
}
__device__ __forceinline__ unsigned pkmul(unsigned a, unsigned b) {
  return __builtin_bit_cast(unsigned,
      (f16x2)(__builtin_bit_cast(f16x2, a) * __builtin_bit_cast(f16x2, b)));
}
__device__ __forceinline__ float ex2(float x) { return __builtin_amdgcn_exp2f(x); }
__device__ __forceinline__ float lg2(float x) { return __builtin_amdgcn_logf(x); }

#define FRAG(B_, k_)                                                           \
  __builtin_bit_cast(f16x8, make_uint4(B_[4*(k_)], B_[4*(k_)+1],               \
                                       B_[4*(k_)+2], B_[4*(k_)+3]))

// ---- kernel 1: full-chip exp pass. EFp word ((b*S+t)*4+g)*16 + 2mt + hi =
// f16x2( exp2(feats[b][t][16mt+4g+2hi+{0,1}] * LOG2E) )
__global__ __launch_bounds__(256)
void crf_expf(const float* __restrict__ feats, unsigned* __restrict__ efp,
              long long n4) {
  long long i = (long long)blockIdx.x * 256 + threadIdx.x;
  if (i >= n4) return;
  int mt = (int)(i & 7);
  long long r = i >> 3;
  int g = (int)(r & 3);
  long long bt = r >> 2;  // b*S + t
  float4 f = *(const float4*)(feats + bt * T2 + 16 * mt + 4 * g);
  uint2 o;
  o.x = pkrtz(ex2(f.x * LOG2E), ex2(f.y * LOG2E));
  o.y = pkrtz(ex2(f.z * LOG2E), ex2(f.w * LOG2E));
  *(uint2*)(efp + 2 * i) = o;
}

// ---- kernel 2: single-wave MFMA scan, zero barriers, no exp in the loop.
// A = exp2(trans*L2E - 8): the 2^-8/step damping cancels the ~2^7.7/step
// growth of sum(exp(feat)) so q stays in f16 range between rescales
// (r8 lesson: WITHOUT it, f16 saturates at 65504 within 3 steps).
// Exact correction +8*S added in the epilogue log2 sum.
__global__ __launch_bounds__(64, 1)
void crf_scan(const unsigned* __restrict__ efp, const float* __restrict__ trans,
              float* __restrict__ out, int S) {
  const int l = threadIdx.x;
  const int c = l & 15, g = l >> 4;
  const int b0 = blockIdx.x * NB;

  __shared__ __align__(16) unsigned char bufA[4096];
  __shared__ __align__(16) unsigned char bufB[4096];

  int wroff[8], rdoff[4];
#pragma unroll
  for (int mt = 0; mt < 8; ++mt)
    wroff[mt] = ((c << 8) + ((16 * mt + 4 * g) << 1)) ^ ((c & 7) << 4);
#pragma unroll
  for (int kk = 0; kk < 4; ++kk)
    rdoff[kk] = ((c << 8) + ((32 * kk + 8 * g) << 1)) ^ ((c & 7) << 4);

  // A frags: exp2(trans*L2E - 8), rows 16mt+c, k slots 32kk+8g+j
  f16x8 A[8][4];
#pragma unroll
  for (int mt = 0; mt < 8; ++mt) {
#pragma unroll
    for (int kk = 0; kk < 4; ++kk) {
      const float* r = trans + (size_t)(16 * mt + c) * T2 + 32 * kk + 8 * g;
      float4 u0 = *(const float4*)r;
      float4 u1 = *(const float4*)(r + 4);
      f16x8 a;
      a[0] = (f16)ex2(fmaf(u0.x, LOG2E, -8.f));
      a[1] = (f16)ex2(fmaf(u0.y, LOG2E, -8.f));
      a[2] = (f16)ex2(fmaf(u0.z, LOG2E, -8.f));
      a[3] = (f16)ex2(fmaf(u0.w, LOG2E, -8.f));
      a[4] = (f16)ex2(fmaf(u1.x, LOG2E, -8.f));
      a[5] = (f16)ex2(fmaf(u1.y, LOG2E, -8.f));
      a[6] = (f16)ex2(fmaf(u1.z, LOG2E, -8.f));
      a[7] = (f16)ex2(fmaf(u1.w, LOG2E, -8.f));
      A[mt][kk] = a;
    }
  }

  // q0 one-hot at k=127 directly in B-frag regs: slot (kk=3, j=7) ->
  // word 15 hi-half, lanes g==3 only.
  unsigned BX[16], BY[16], qd[16];
#pragma unroll
  for (int i = 0; i < 16; ++i) BX[i] = 0u;
  BX[15] = (g == 3) ? 0x3C000000u : 0u;

  const unsigned* efb = efp + (size_t)(b0 + c) * S * 64 + (size_t)g * 16;
  unsigned EAw[16], EBw[16];
#pragma unroll
  for (int j = 0; j < 4; ++j) *(uint4*)&EAw[4 * j] = *(const uint4*)(efb + 4 * j);
#pragma unroll
  for (int j = 0; j < 4; ++j) *(uint4*)&EBw[4 * j] = *(const uint4*)(efb + 64 + 4 * j);

  float log2acc = 0.f;

#define STEP(T_, BUFW, BIN, BOUT, EC, EN)                                      \
  {                                                                            \
    const int t_ = (T_);                                                       \
    /* issue EF reload for step t_+2 FIRST (independent; overlaps MFMAs); */   \
    /* lands in EC, which was fully consumed... after the MFMA loop below */   \
    unsigned NR0, NR1, NR2, NR3, NR4, NR5, NR6, NR7,                           \
             NR8, NR9, NR10, NR11, NR12, NR13, NR14, NR15;                     \
    {                                                                          \
      int tl_ = t_ + 2; if (tl_ > S - 1) tl_ = S - 1;                          \
      const unsigned* p_ = efb + (size_t)tl_ * 64;                             \
      uint4 u0_ = *(const uint4*)(p_);                                         \
      uint4 u1_ = *(const uint4*)(p_ + 4);                                     \
      uint4 u2_ = *(const uint4*)(p_ + 8);                                     \
      uint4 u3_ = *(const uint4*)(p_ + 12);                                    \
      NR0 = u0_.x; NR1 = u0_.y; NR2 = u0_.z; NR3 = u0_.w;                      \
      NR4 = u1_.x; NR5 = u1_.y; NR6 = u1_.z; NR7 = u1_.w;                      \
      NR8 = u2_.x; NR9 = u2_.y; NR10 = u2_.z; NR11 = u2_.w;                    \
      NR12 = u3_.x; NR13 = u3_.y; NR14 = u3_.z; NR15 = u3_.w;                  \
    }                                                                          \
    _Pragma("unroll")                                                          \
    for (int mt = 0; mt < 8; ++mt) {                                           \
      f32x4 a0 = {0.f, 0.f, 0.f, 0.f}, a1 = {0.f, 0.f, 0.f, 0.f};              \
      a0 = __builtin_amdgcn_mfma_f32_16x16x32_f16(A[mt][0], FRAG(BIN, 0), a0, 0, 0, 0); \
      a0 = __builtin_amdgcn_mfma_f32_16x16x32_f16(A[mt][1], FRAG(BIN, 1), a0, 0, 0, 0); \
      a1 = __builtin_amdgcn_mfma_f32_16x16x32_f16(A[mt][2], FRAG(BIN, 2), a1, 0, 0, 0); \
      a1 = __builtin_amdgcn_mfma_f32_16x16x32_f16(A[mt][3], FRAG(BIN, 3), a1, 0, 0, 0); \
      qd[2*mt]   = pkmul(pkrtz(a0[0] + a1[0], a0[1] + a1[1]), EC[2*mt]);       \
      qd[2*mt+1] = pkmul(pkrtz(a0[2] + a1[2], a0[3] + a1[3]), EC[2*mt+1]);     \
      *(uint2*)(BUFW + wroff[mt]) = make_uint2(qd[2*mt], qd[2*mt+1]);          \
      if (mt & 1) {                                                            \
        uint4 u = *(const uint4*)(BUFW + rdoff[mt >> 1]);                      \
        BOUT[4*(mt>>1)+0] = u.x; BOUT[4*(mt>>1)+1] = u.y;                      \
        BOUT[4*(mt>>1)+2] = u.z; BOUT[4*(mt>>1)+3] = u.w;                      \
      }                                                                        \
    }                                                                          \
    EC[0] = NR0; EC[1] = NR1; EC[2] = NR2; EC[3] = NR3;                        \
    EC[4] = NR4; EC[5] = NR5; EC[6] = NR6; EC[7] = NR7;                        \
    EC[8] = NR8; EC[9] = NR9; EC[10] = NR10; EC[11] = NR11;                    \
    EC[12] = NR12; EC[13] = NR13; EC[14] = NR14; EC[15] = NR15;                \
    if ((t_ & 7) == 7 && t_ != S - 1) { /* l1 rescale folded into EF(t_+1) */  \
      f16x2 sv = __builtin_bit_cast(f16x2, qd[0]);                             \
      _Pragma("unroll")                                                        \
      for (int i_ = 1; i_ < 16; ++i_) sv = sv + __builtin_bit_cast(f16x2, qd[i_]); \
      float s_ = (float)sv.x + (float)sv.y;                                    \
      s_ += __shfl_xor(s_, 16);                                                \
      s_ += __shfl_xor(s_, 32);                                                \
      s_ = fmaxf(s_, 1e-30f);                                                  \
      float inv_ = 1.0f / s_;                                                  \
      unsigned ip_ = pkrtz(inv_, inv_);                                        \
      _Pragma("unroll")                                                        \
      for (int i_ = 0; i_ < 16; ++i_) EN[i_] = pkmul(EN[i_], ip_);             \
      log2acc += lg2(s_);                                                      \
    }                                                                          \
  }

  for (int t = 0; t < S; t += 2) {
    STEP(t,     bufB, BX, BY, EAw, EBw)
    STEP(t + 1, bufA, BY, BX, EBw, EAw)
  }
#undef STEP

  // epilogue: BX = q_S (B layout); +8*S undoes the per-step 2^-8 damping
  float p = 0.f;
#pragma unroll
  for (int kk = 0; kk < 4; ++kk) {
    const float* r = trans + (size_t)(T2 - 2) * T2 + 32 * kk + 8 * g;
    float4 u0 = *(const float4*)r;
    float4 u1 = *(const float4*)(r + 4);
    f16x2 h0 = __builtin_bit_cast(f16x2, BX[kk * 4 + 0]);
    f16x2 h1 = __builtin_bit_cast(f16x2, BX[kk * 4 + 1]);
    f16x2 h2 = __builtin_bit_cast(f16x2, BX[kk * 4 + 2]);
    f16x2 h3 = __builtin_bit_cast(f16x2, BX[kk * 4 + 3]);
    p += (float)h0.x * ex2(u0.x * LOG2E) + (float)h0.y * ex2(u0.y * LOG2E);
    p += (float)h1.x * ex2(u0.z * LOG2E) + (float)h1.y * ex2(u0.w * LOG2E);
    p += (float)h2.x * ex2(u1.x * LOG2E) + (float)h2.y * ex2(u1.y * LOG2E);
    p += (float)h3.x * ex2(u1.z * LOG2E) + (float)h3.y * ex2(u1.w * LOG2E);
  }
  p += __shfl_xor(p, 16);
  p += __shfl_xor(p, 32);
  if (l < 16)
    out[b0 + l] = (lg2(fmaxf(p, 1e-30f)) + log2acc + 8.0f * (float)S) * LN2;
}

// ---- fallback (ws too small): round-7 kernel verbatim (passed, 753us)
__global__ __launch_bounds__(64, 1)
void crf_fused(const float* __restrict__ feats, const float* __restrict__ trans,
               float* __restrict__ out, int S) {
  const int l  = threadIdx.x;
  const int c  = l & 15;
  const int g  = l >> 4;
  const int b0 = blockIdx.x * NB;

  __shared__ __align__(16) unsigned char bufA[4096];
  __shared__ __align__(16) unsigned char bufB[4096];

  int wroff[8], rdoff[4];
#pragma unroll
  for (int mt = 0; mt < 8; ++mt)
    wroff[mt] = ((c << 8) + ((16 * mt + 4 * g) << 1)) ^ ((c & 7) << 4);
#pragma unroll
  for (int kk = 0; kk < 4; ++kk)
    rdoff[kk] = ((c << 8) + ((32 * kk + 8 * g) << 1)) ^ ((c & 7) << 4);

  f16x8 A[8][4];
#pragma unroll
  for (int mt = 0; mt < 8; ++mt) {
#pragma unroll
    for (int kk = 0; kk < 4; ++kk) {
      const float* r = trans + (size_t)(16 * mt + c) * T2 + 32 * kk + 8 * g;
      float4 u0 = *(const float4*)r;
      float4 u1 = *(const float4*)(r + 4);
      f16x8 a;
      a[0] = (f16)ex2(fmaf(u0.x, LOG2E, -8.f));
      a[1] = (f16)ex2(fmaf(u0.y, LOG2E, -8.f));
      a[2] = (f16)ex2(fmaf(u0.z, LOG2E, -8.f));
      a[3] = (f16)ex2(fmaf(u0.w, LOG2E, -8.f));
      a[4] = (f16)ex2(fmaf(u1.x, LOG2E, -8.f));
      a[5] = (f16)ex2(fmaf(u1.y, LOG2E, -8.f));
      a[6] = (f16)ex2(fmaf(u1.z, LOG2E, -8.f));
      a[7] = (f16)ex2(fmaf(u1.w, LOG2E, -8.f));
      A[mt][kk] = a;
    }
  }

#pragma unroll
  for (int i = 0; i < 4; ++i)
    *(uint4*)(bufA + l * 16 + i * 1024) = make_uint4(0, 0, 0, 0);
  if (l < 16)
    *(unsigned short*)(bufA + ((((l << 8) + 254)) ^ ((l & 7) << 4))) = 0x3C00;

  unsigned BX[16], BY[16];
#pragma unroll
  for (int kk = 0; kk < 4; ++kk) {
    uint4 u = *(const uint4*)(bufA + rdoff[kk]);
    BX[kk * 4 + 0] = u.x; BX[kk * 4 + 1] = u.y;
    BX[kk * 4 + 2] = u.z; BX[kk * 4 + 3] = u.w;
  }

  const float* fb = feats + ((size_t)(b0 + c) * S) * T2 + 4 * g;
  float4 PA[8], PB[8];
#pragma unroll
  for (int mt = 0; mt < 8; ++mt) PA[mt] = *(const float4*)(fb + 16 * mt);
#pragma unroll
  for (int mt = 0; mt < 8; ++mt) PB[mt] = *(const float4*)(fb + T2 + 16 * mt);
  unsigned EA[16], EB[16];
#pragma unroll
  for (int mt = 0; mt < 8; ++mt) {
    EA[2 * mt]     = pkrtz(ex2(PA[mt].x * LOG2E), ex2(PA[mt].y * LOG2E));
    EA[2 * mt + 1] = pkrtz(ex2(PA[mt].z * LOG2E), ex2(PA[mt].w * LOG2E));
  }

  float log2acc = 0.f;

#define FBODY(T, BUFW, BIN, BOUT, PC, PN, EC, EN)                              \
  {                                                                            \
    const int t_ = (T);                                                        \
    {                                                                          \
      int tl = t_ + 2; if (tl > S - 1) tl = S - 1;                             \
      const float* fp_ = fb + (size_t)tl * T2;                                 \
      _Pragma("unroll")                                                        \
      for (int mt = 0; mt < 8; ++mt) PC[mt] = *(const float4*)(fp_ + 16 * mt); \
    }                                                                          \
    unsigned qd[16];                                                           \
    _Pragma("unroll")                                                          \
    for (int mt = 0; mt < 8; ++mt) {                                           \
      f32x4 acc = {0.f, 0.f, 0.f, 0.f};                                        \
      _Pragma("unroll")                                                        \
      for (int kk = 0; kk < 4; ++kk) {                                         \
        uint4 bu = make_uint4(BIN[kk * 4 + 0], BIN[kk * 4 + 1],                \
                              BIN[kk * 4 + 2], BIN[kk * 4 + 3]);               \
        acc = __builtin_amdgcn_mfma_f32_16x16x32_f16(                          \
            A[mt][kk], __builtin_bit_cast(f16x8, bu), acc, 0, 0, 0);           \
      }                                                                        \
      qd[2 * mt]     = pkmul(pkrtz(acc[0], acc[1]), EC[2 * mt]);               \
      qd[2 * mt + 1] = pkmul(pkrtz(acc[2], acc[3]), EC[2 * mt + 1]);           \
      *(uint2*)(BUFW + wroff[mt]) = make_uint2(qd[2 * mt], qd[2 * mt + 1]);    \
      if (mt & 1) {                                                            \
        uint4 u = *(const uint4*)(BUFW + rdoff[mt >> 1]);                      \
        BOUT[(mt >> 1) * 4 + 0] = u.x; BOUT[(mt >> 1) * 4 + 1] = u.y;          \
        BOUT[(mt >> 1) * 4 + 2] = u.z; BOUT[(mt >> 1) * 4 + 3] = u.w;          \
      }                                                                        \
    }                                                                          \
    _Pragma("unroll")                                                          \
    for (int mt = 0; mt < 8; ++mt) {                                           \
      EN[2 * mt]     = pkrtz(ex2(PN[mt].x * LOG2E), ex2(PN[mt].y * LOG2E));    \
      EN[2 * mt + 1] = pkrtz(ex2(PN[mt].z * LOG2E), ex2(PN[mt].w * LOG2E));    \
    }                                                                          \
    if (((t_ & 7) == 7) && (t_ != S - 1)) {                                    \
      f16x2 sv = __builtin_bit_cast(f16x2, qd[0]);                             \
      _Pragma("unroll")                                                        \
      for (int i = 1; i < 16; ++i) sv = sv + __builtin_bit_cast(f16x2, qd[i]); \
      float s_ = (float)sv.x + (float)sv.y;                                    \
      s_ += __shfl_xor(s_, 16);                                                \
      s_ += __shfl_xor(s_, 32);                                                \
      s_ = fmaxf(s_, 1e-4f);                                                   \
      float inv_ = 1.0f / s_;                                                  \
      unsigned ip_ = pkrtz(inv_, inv_);                                        \
      _Pragma("unroll")                                                        \
      for (int i = 0; i < 16; ++i) EN[i] = pkmul(EN[i], ip_);                  \
      log2acc += lg2(s_);                                                      \
    }                                                                          \
  }

  for (int t = 0; t < S; t += 2) {
    FBODY(t,     bufB, BX, BY, PA, PB, EA, EB)
    FBODY(t + 1, bufA, BY, BX, PB, PA, EB, EA)
  }
#undef FBODY

  float p = 0.f;
#pragma unroll
  for (int kk = 0; kk < 4; ++kk) {
    const float* r = trans + (size_t)(T2 - 2) * T2 + 32 * kk + 8 * g;
    float4 u0 = *(const float4*)r;
    float4 u1 = *(const float4*)(r + 4);
    f16x2 h0 = __builtin_bit_cast(f16x2, BX[kk * 4 + 0]);
    f16x2 h1 = __builtin_bit_cast(f16x2, BX[kk * 4 + 1]);
    f16x2 h2 = __builtin_bit_cast(f16x2, BX[kk * 4 + 2]);
    f16x2 h3 = __builtin_bit_cast(f16x2, BX[kk * 4 + 3]);
    p += (float)h0.x * ex2(u0.x * LOG2E) + (float)h0.y * ex2(u0.y * LOG2E);
    p += (float)h1.x * ex2(u0.z * LOG2E) + (float)h1.y * ex2(u0.w * LOG2E);
    p += (float)h2.x * ex2(u1.x * LOG2E) + (float)h2.y * ex2(u1.y * LOG2E);
    p += (float)h3.x * ex2(u1.z * LOG2E) + (float)h3.y * ex2(u1.w * LOG2E);
  }
  p += __shfl_xor(p, 16);
  p += __shfl_xor(p, 32);
  if (l < 16)
    out[b0 + l] =
        (lg2(fmaxf(p, 1e-30f)) + log2acc + 8.0f * (float)S) * LN2;
}

extern "C" void kernel_launch(void* const* d_in, const int* in_sizes, int n_in,
                              void* d_out, int out_size, void* d_ws, size_t ws_size,
                              hipStream_t stream) {
  const float* feats = (const float*)d_in[0];
  const float* trans = (const float*)d_in[1];
  float* out = (float*)d_out;
  const int B = out_size;                // 256
  const int S = in_sizes[0] / (B * T2);  // 1024

  const size_t need = (size_t)B * S * T2 * 2;  // 64 MB f16 EF table
  if (d_ws && ws_size >= need) {
    unsigned* efp = (unsigned*)d_ws;
    long long n4 = (long long)B * S * 32;
    crf_expf<<<dim3((unsigned)((n4 + 255) / 256)), dim3(256), 0, stream>>>(feats, efp, n4);
    crf_scan<<<dim3(B / NB), dim3(64), 0, stream>>>(efp, trans, out, S);
  } else {
    crf_fused<<<dim3(B / NB), dim3(64), 0, stream>>>(feats, trans, out, S);
  }
}